// Round 1
// baseline (182.461 us; speedup 1.0000x reference)
//
#include <hip/hip_runtime.h>

// Cholesky-from-partial-correlations.
//   out[b,i,j] = z_j * sqrt( prod_{k<j} (1 - z_k^2) )  for j < i;  1 on diag; 0 above.
// v2: TWO rows per wave (rows 2w, 2w+1) -> two independent 1KiB loads + two
// 1KiB stores in flight per wave (2x MLP at unchanged occupancy), XCD-contiguous
// block swizzle so the packed-row over-read dedupes inside one L2, and
// nontemporal stores so the 134MB write stream doesn't evict the input.
// Wave prefix product via all-VALU DPP scan; short rows skip bcast steps
// (wave-uniform branches since i0 is even). Raw v_sqrt_f32 (error budget >> 1 ulp).

#define SIZE 256
#define BATCH 512
#define M (SIZE * (SIZE - 1) / 2)        // 32640
#define TOTAL (BATCH * M)                // 16711680
#define NWAVES (BATCH * SIZE / 2)        // 65536 waves, 2 rows each
#define NBLOCKS (NWAVES / 4)             // 16384 blocks of 4 waves

// 4-byte-aligned float4 — lets the backend emit an unaligned dwordx4
typedef float f4u __attribute__((ext_vector_type(4), aligned(4)));
// 16-byte-aligned float4 for the output stores
typedef float f4a __attribute__((ext_vector_type(4), aligned(16)));

// p *= dpp_shifted(p); invalid lanes contribute 1.0f (identity) via `old`
template <int CTRL, int ROW_MASK>
__device__ __forceinline__ float scan_mul(float p) {
    int sh = __builtin_amdgcn_update_dpp(
        __builtin_bit_cast(int, 1.0f),
        __builtin_bit_cast(int, p),
        CTRL, ROW_MASK, 0xF, false);
    return p * __builtin_bit_cast(float, sh);
}

// whole-wave shift right by 1; lane 0 gets 1.0f (exclusive-scan carry-in)
__device__ __forceinline__ float excl_shift_one(float p) {
    int r = __builtin_amdgcn_update_dpp(
        __builtin_bit_cast(int, 1.0f),
        __builtin_bit_cast(int, p),
        0x138 /* wave_shr:1 */, 0xF, 0xF, false);
    return __builtin_bit_cast(float, r);
}

__global__ __launch_bounds__(256) void chol_from_z_kernel(
    const float* __restrict__ vec, float* __restrict__ out) {
    const int lane = threadIdx.x & 63;
    const int wib = __builtin_amdgcn_readfirstlane((int)threadIdx.x >> 6);

    // XCD-contiguous swizzle: each of the 8 XCDs gets 2048 consecutive blocks
    // of the original work order -> the 2x packed-row over-read hits one L2.
    const int bid = (int)blockIdx.x;
    const int sbid = (bid & 7) * (NBLOCKS / 8) + (bid >> 3);   // bijective

    const int wave = sbid * 4 + wib;        // 0 .. NWAVES-1
    const int r0 = wave << 1;               // even global row index
    const int b = r0 >> 8;                  // batch
    const int i0 = r0 & 255;                // even row
    const int i1 = i0 + 1;                  // odd row
    const int off0 = b * M + ((i0 * (i0 - 1)) >> 1);
    const int off1 = off0 + i0;             // off(i+1) = off(i) + i
    const float* __restrict__ sA = vec + off0;
    const float* __restrict__ sB = vec + off1;
    float* __restrict__ dst = out + ((size_t)r0 << 8);
    const int j0 = lane << 2;

    // ---- two independent vector loads, issued back-to-back (2x MLP) ----
    // Row 0 of the pair is never the globally-last row (that one is odd),
    // so its full 1KiB window is always in-bounds.
    f4u za = *(const f4u*)(sA + j0);
    f4u zb;
    if (off1 + 255 < TOTAL) {               // wave-uniform: all but last row
        zb = *(const f4u*)(sB + j0);
    } else {                                // only the global-last row's wave
        const int maxidx = (TOTAL - 1) - off1;
        zb.x = sB[j0]; zb.y = sB[j0 + 1]; zb.z = sB[j0 + 2];
        zb.w = (j0 + 3 <= maxidx) ? sB[j0 + 3] : 0.f;
    }

    // mask to strictly-lower region (garbage past row end is masked here)
    const float a0 = (j0     < i0) ? za.x : 0.f;
    const float a1 = (j0 + 1 < i0) ? za.y : 0.f;
    const float a2 = (j0 + 2 < i0) ? za.z : 0.f;
    const float a3 = (j0 + 3 < i0) ? za.w : 0.f;
    const float b0 = (j0     < i1) ? zb.x : 0.f;
    const float b1 = (j0 + 1 < i1) ? zb.y : 0.f;
    const float b2 = (j0 + 2 < i1) ? zb.z : 0.f;
    const float b3 = (j0 + 3 < i1) ? zb.w : 0.f;

    const float tA0 = 1.f - a0 * a0, tA1 = 1.f - a1 * a1;
    const float tA2 = 1.f - a2 * a2, tA3 = 1.f - a3 * a3;
    const float tB0 = 1.f - b0 * b0, tB1 = 1.f - b1 * b1;
    const float tB2 = 1.f - b2 * b2, tB3 = 1.f - b3 * b3;

    float pA = (tA0 * tA1) * (tA2 * tA3);
    float pB = (tB0 * tB1) * (tB2 * tB3);

    // wave64 inclusive prefix product — two independent DPP chains interleave,
    // hiding DPP latency. Rows with the diagonal inside the first 16/32 lanes
    // skip bcast steps (wave-uniform: i0 even => i0>=64 <=> i1>=64, same for 128).
    pA = scan_mul<0x111, 0xF>(pA);  pB = scan_mul<0x111, 0xF>(pB);   // row_shr:1
    pA = scan_mul<0x112, 0xF>(pA);  pB = scan_mul<0x112, 0xF>(pB);   // row_shr:2
    pA = scan_mul<0x114, 0xF>(pA);  pB = scan_mul<0x114, 0xF>(pB);   // row_shr:4
    pA = scan_mul<0x118, 0xF>(pA);  pB = scan_mul<0x118, 0xF>(pB);   // row_shr:8
    if (i0 >= 64)  { pA = scan_mul<0x142, 0xA>(pA);                  // bcast:15
                     pB = scan_mul<0x142, 0xA>(pB); }
    if (i0 >= 128) { pA = scan_mul<0x143, 0xC>(pA);                  // bcast:31
                     pB = scan_mul<0x143, 0xC>(pB); }

    float runA = excl_shift_one(pA);
    float runB = excl_shift_one(pB);

    f4a oA, oB;
    oA.x = (j0     == i0) ? 1.f : a0 * __builtin_amdgcn_sqrtf(runA); runA *= tA0;
    oB.x = (j0     == i1) ? 1.f : b0 * __builtin_amdgcn_sqrtf(runB); runB *= tB0;
    oA.y = (j0 + 1 == i0) ? 1.f : a1 * __builtin_amdgcn_sqrtf(runA); runA *= tA1;
    oB.y = (j0 + 1 == i1) ? 1.f : b1 * __builtin_amdgcn_sqrtf(runB); runB *= tB1;
    oA.z = (j0 + 2 == i0) ? 1.f : a2 * __builtin_amdgcn_sqrtf(runA); runA *= tA2;
    oB.z = (j0 + 2 == i1) ? 1.f : b2 * __builtin_amdgcn_sqrtf(runB); runB *= tB2;
    oA.w = (j0 + 3 == i0) ? 1.f : a3 * __builtin_amdgcn_sqrtf(runA);
    oB.w = (j0 + 3 == i1) ? 1.f : b3 * __builtin_amdgcn_sqrtf(runB);

    // streaming stores: don't let the 134MB write stream evict the input
    __builtin_nontemporal_store(oA, (f4a*)(dst + j0));          // row i0
    __builtin_nontemporal_store(oB, (f4a*)(dst + SIZE + j0));   // row i1
}

extern "C" void kernel_launch(void* const* d_in, const int* in_sizes, int n_in,
                              void* d_out, int out_size, void* d_ws, size_t ws_size,
                              hipStream_t stream) {
    const float* vec = (const float*)d_in[0];
    float* out = (float*)d_out;
    chol_from_z_kernel<<<NBLOCKS, 256, 0, stream>>>(vec, out);
}

// Round 3
// 180.760 us; speedup vs baseline: 1.0094x; 1.0094x over previous
//
#include <hip/hip_runtime.h>

// Cholesky-from-partial-correlations.
//   out[b,i,j] = z_j * sqrt( prod_{k<j} (1 - z_k^2) )  for j < i;  1 on diag; 0 above.
// v3: back to 1 row/wave with NORMAL cached stores (v2's nontemporal stores
// forced the 134MB output to HBM (~20us drain) instead of Infinity Cache —
// the whole working set (67MB in + 134MB out) is L3-resident, so stores must
// stay cached). Kept: XCD-contiguous block swizzle (overlapping row windows
// dedupe in one XCD's L2 instead of 8x L3 re-fetch). New: fully-invalid lanes
// clamp their load address to the row start — free same-line broadcast —
// halving read demand from 134MB (full 1KiB window per row) to ~67MB unique.
// Wave prefix product via all-VALU DPP scan; short rows skip bcast steps
// (wave-uniform branches). Raw v_sqrt_f32 (error budget 2e-2 >> 1 ulp).

#define SIZE 256
#define BATCH 512
#define M (SIZE * (SIZE - 1) / 2)   // 32640
#define TOTAL (BATCH * M)           // 16711680
#define NWAVES (BATCH * SIZE)       // 131072 rows, 1 wave each
#define NBLOCKS (NWAVES / 4)        // 32768 blocks of 4 waves

// 4-byte-aligned float4 — lets the backend emit an unaligned dwordx4
typedef float f4u __attribute__((ext_vector_type(4), aligned(4)));
// 16-byte-aligned float4 for the output stores
typedef float f4a __attribute__((ext_vector_type(4), aligned(16)));

// p *= dpp_shifted(p); invalid lanes contribute 1.0f (identity) via `old`
template <int CTRL, int ROW_MASK>
__device__ __forceinline__ float scan_mul(float p) {
    int sh = __builtin_amdgcn_update_dpp(
        __builtin_bit_cast(int, 1.0f),
        __builtin_bit_cast(int, p),
        CTRL, ROW_MASK, 0xF, false);
    return p * __builtin_bit_cast(float, sh);
}

// whole-wave shift right by 1; lane 0 gets 1.0f (exclusive-scan carry-in)
__device__ __forceinline__ float excl_shift_one(float p) {
    int r = __builtin_amdgcn_update_dpp(
        __builtin_bit_cast(int, 1.0f),
        __builtin_bit_cast(int, p),
        0x138 /* wave_shr:1 */, 0xF, 0xF, false);
    return __builtin_bit_cast(float, r);
}

__global__ __launch_bounds__(256) void chol_from_z_kernel(
    const float* __restrict__ vec, float* __restrict__ out) {
    const int lane = threadIdx.x & 63;
    const int wib = __builtin_amdgcn_readfirstlane((int)threadIdx.x >> 6);

    // XCD-contiguous swizzle: each of the 8 XCDs gets NBLOCKS/8 consecutive
    // blocks of the original order -> overlapping row windows share one L2.
    const int bid = (int)blockIdx.x;
    const int sbid = (bid & 7) * (NBLOCKS / 8) + (bid >> 3);   // bijective

    const int wave = sbid * 4 + wib;              // 0 .. NWAVES-1
    const int b = wave >> 8;                      // batch
    const int i = wave & 255;                     // row
    const int row_off = b * M + ((i * (i - 1)) >> 1);
    const float* __restrict__ s = vec + row_off;
    float* __restrict__ dst = out + ((size_t)wave << 8);
    const int j0 = lane << 2;

    // ---- single vector load per lane ----
    // Lanes entirely past the row end re-read the row start: same cache line
    // as lane 0 -> zero extra traffic, and keeps every access inside the
    // row's real data except lane 63 of the globally-last row.
    const int ja = (j0 < i) ? j0 : 0;
    const int maxidx = (TOTAL - 1) - row_off;     // wave-uniform
    f4u zv;
    if (maxidx >= 255) {                          // all waves but the last row's
        zv = *(const f4u*)(s + ja);
    } else {                                      // globally-last row only
        zv.x = s[ja]; zv.y = s[ja + 1]; zv.z = s[ja + 2];
        zv.w = (ja + 3 <= maxidx) ? s[ja + 3] : 0.f;
    }

    // mask to strictly-lower region (clamped/garbage lanes -> 0)
    const float z0 = (j0     < i) ? zv.x : 0.f;
    const float z1 = (j0 + 1 < i) ? zv.y : 0.f;
    const float z2 = (j0 + 2 < i) ? zv.z : 0.f;
    const float z3 = (j0 + 3 < i) ? zv.w : 0.f;

    const float t0 = 1.f - z0 * z0;
    const float t1 = 1.f - z1 * z1;
    const float t2 = 1.f - z2 * z2;
    const float t3 = 1.f - z3 * z3;

    float p = (t0 * t1) * (t2 * t3);

    // wave64 inclusive prefix product — up to 6 VALU DPP steps;
    // rows with diagonal inside the first 16/32 lanes skip bcast steps
    p = scan_mul<0x111, 0xF>(p);                  // row_shr:1
    p = scan_mul<0x112, 0xF>(p);                  // row_shr:2
    p = scan_mul<0x114, 0xF>(p);                  // row_shr:4
    p = scan_mul<0x118, 0xF>(p);                  // row_shr:8
    if (i >= 64)  p = scan_mul<0x142, 0xA>(p);    // row_bcast:15 -> rows 1,3
    if (i >= 128) p = scan_mul<0x143, 0xC>(p);    // row_bcast:31 -> rows 2,3

    float run = excl_shift_one(p);

    f4a o;
    o.x = (j0     == i) ? 1.f : z0 * __builtin_amdgcn_sqrtf(run); run *= t0;
    o.y = (j0 + 1 == i) ? 1.f : z1 * __builtin_amdgcn_sqrtf(run); run *= t1;
    o.z = (j0 + 2 == i) ? 1.f : z2 * __builtin_amdgcn_sqrtf(run); run *= t2;
    o.w = (j0 + 3 == i) ? 1.f : z3 * __builtin_amdgcn_sqrtf(run);

    *(f4a*)(dst + j0) = o;        // dst 1 KiB-aligned, j0*4 is 16B multiple
}

extern "C" void kernel_launch(void* const* d_in, const int* in_sizes, int n_in,
                              void* d_out, int out_size, void* d_ws, size_t ws_size,
                              hipStream_t stream) {
    const float* vec = (const float*)d_in[0];
    float* out = (float*)d_out;
    chol_from_z_kernel<<<NBLOCKS, 256, 0, stream>>>(vec, out);
}